// Round 4
// baseline (57.205 us; speedup 1.0000x reference)
//
#include <hip/hip_runtime.h>
#include <math.h>

#define B 32
#define C 4
#define CF 5
#define NPAIR 496      // 32*31/2 unordered pairs (diagonal JS == 0)
#define TL 8           // l-positions per block
#define NTHR 256       // = B * TL exactly: one (b,l) row per thread

// Single fused kernel: per-block w-table (redundant, cheap), coalesced staging,
// CE + R2 + pairwise-JS, block partials, last-block final reduction.
__global__ __launch_bounds__(NTHR) void k_all(const float* __restrict__ logits,
                                              const float* __restrict__ prob,
                                              const float* __restrict__ y_true,
                                              const float* __restrict__ yevo,
                                              float* __restrict__ partials,
                                              unsigned* __restrict__ counter,
                                              float* __restrict__ out,
                                              int L, int nblk) {
    const int t = threadIdx.x;
    const int blk = blockIdx.x;
    const int l0 = blk * TL;

    __shared__ float w[1024];          // evo weight matrix
    __shared__ float4 sp4[TL][32];     // clamped probs
    __shared__ float splogp[TL][32];   // sum p*log p
    __shared__ int   slbl[TL][32];
    __shared__ float wred[4][5];
    __shared__ unsigned done;

    // ---- phase 0: w = exp(-2y)/(rowsum+eps); 256 thr x 4 elems = 1024 ----
    {
        float4 y = *(const float4*)(yevo + 4 * t);   // row i = t>>3
        float e0 = __expf(-2.f * y.x), e1 = __expf(-2.f * y.y);
        float e2 = __expf(-2.f * y.z), e3 = __expf(-2.f * y.w);
        float s = e0 + e1 + e2 + e3;
        s += __shfl_xor(s, 1);
        s += __shfl_xor(s, 2);
        s += __shfl_xor(s, 4);                       // row sum over 8 lanes
        float inv = 1.0f / (s + 1e-8f);
        *(float4*)&w[4 * t] = make_float4(e0 * inv, e1 * inv, e2 * inv, e3 * inv);
    }

    // ---- phase 1: staging + CE + R2; thread t -> (b = t>>3, ll = t&7) ----
    float ce = 0.f, valid = 0.f, r2s = 0.f, tv = 0.f;
    {
        const int b = t >> 3, ll = t & 7;            // b in [0,32)
        const int l = l0 + ll;
        const float* yt = y_true + ((size_t)b * L + l) * CF;
        float y0 = yt[0], y1 = yt[1], y2 = yt[2], y3 = yt[3], y4 = yt[4];
        int lbl = 0; float best = y0;
        if (y1 > best) { best = y1; lbl = 1; }
        if (y2 > best) { best = y2; lbl = 2; }
        if (y3 > best) { best = y3; lbl = 3; }
        if (y4 > best) { best = y4; lbl = 4; }
        float salt = y1 + y2 + y3;

        float4 pv = *(const float4*)(prob + ((size_t)b * L + l) * C);
        float spalt = pv.y + pv.z + pv.w;            // raw probs per reference
        float q0 = fmaxf(pv.x, 1e-7f), q1 = fmaxf(pv.y, 1e-7f);
        float q2 = fmaxf(pv.z, 1e-7f), q3 = fmaxf(pv.w, 1e-7f);
        float plp = q0 * __logf(q0) + q1 * __logf(q1)
                  + q2 * __logf(q2) + q3 * __logf(q3);
        sp4[ll][b] = make_float4(q0, q1, q2, q3);
        splogp[ll][b] = plp;
        slbl[ll][b] = lbl;

        if (lbl != 4) {
            float4 av = *(const float4*)(logits + ((size_t)b * L + l) * C);
            float mx = fmaxf(fmaxf(av.x, av.y), fmaxf(av.z, av.w));
            float se = __expf(av.x - mx) + __expf(av.y - mx)
                     + __expf(av.z - mx) + __expf(av.w - mx);
            float lse = mx + __logf(se);
            float al = (lbl == 0) ? av.x : (lbl == 1) ? av.y
                     : (lbl == 2) ? av.z : av.w;
            ce = lse - al;
            valid = 1.f;
        }

        // R2: group of 4 = b bits 0,1 = t bits 3,4 (within the 64-lane wave)
        float nmc = (lbl != 4) ? 1.f : 0.f, altc = salt, ps = spalt;
        nmc  += __shfl_xor(nmc, 8);   nmc  += __shfl_xor(nmc, 16);
        altc += __shfl_xor(altc, 8);  altc += __shfl_xor(altc, 16);
        ps   += __shfl_xor(ps, 8);    ps   += __shfl_xor(ps, 16);
        float af = altc / fmaxf(nmc, 1.f);
        float pred = 0.25f * ps;
        bool miss = (lbl == 4);
        float taf = miss ? 0.5f : af;
        bool edge = (taf == 0.f) || (taf == 1.f);
        float denom = fmaxf(taf * (1.f - taf), 0.01f);
        float d = pred - taf;
        float r2 = d * d / denom;
        if (edge || miss) r2 = 0.f;
        r2s -= r2;
        if (nmc > 0.f && r2 != 0.f) tv += 1.f;
    }
    __syncthreads();

    // ---- phase 2: 496 pairs per l; 32 lanes per l (ll = t>>5) ----
    float evo = 0.f;
    {
        const int ll = t >> 5, pl = t & 31;
        #pragma unroll
        for (int it = 0; it < 16; ++it) {
            int s = it * 32 + pl;
            if (s < NPAIR) {
                int r = s >> 4, k = s & 15;          // round-robin tournament
                int i, j;
                if (k == 0) { i = 31; j = r; }
                else {
                    i = r + k;        if (i >= 31) i -= 31;
                    j = r + 31 - k;   if (j >= 31) j -= 31;
                }
                int li = slbl[ll][i];
                if (li == slbl[ll][j] && li != 4) {
                    float4 a = sp4[ll][i], bq = sp4[ll][j];
                    float m0 = 0.5f * (a.x + bq.x), m1 = 0.5f * (a.y + bq.y);
                    float m2 = 0.5f * (a.z + bq.z), m3 = 0.5f * (a.w + bq.w);
                    float mlogm = m0 * __logf(m0) + m1 * __logf(m1)
                                + m2 * __logf(m2) + m3 * __logf(m3);
                    float js = 0.5f * (splogp[ll][i] + splogp[ll][j]) - mlogm;
                    evo += (w[i * 32 + j] + w[j * 32 + i]) * js;
                }
            }
        }
    }

    // ---- block reduction of 5 accumulators ----
    #pragma unroll
    for (int off = 32; off; off >>= 1) {
        ce += __shfl_xor(ce, off);   valid += __shfl_xor(valid, off);
        r2s += __shfl_xor(r2s, off); tv += __shfl_xor(tv, off);
        evo += __shfl_xor(evo, off);
    }
    const int wv = t >> 6;
    if ((t & 63) == 0) {
        wred[wv][0] = ce; wred[wv][1] = valid; wred[wv][2] = r2s;
        wred[wv][3] = tv; wred[wv][4] = evo;
    }
    __syncthreads();
    if (t == 0) {
        #pragma unroll
        for (int a = 0; a < 5; ++a)
            partials[a * nblk + blk] = wred[0][a] + wred[1][a]
                                     + wred[2][a] + wred[3][a];
    }

    // ---- last-block-done: final reduction + epilogue ----
    __threadfence();                       // release partials device-wide
    if (t == 0) done = atomicAdd(counter, 1u);
    __syncthreads();
    if (done != (unsigned)(nblk - 1)) return;
    __threadfence();                       // acquire others' partials

    float s0 = 0.f, s1 = 0.f, s2 = 0.f, s3 = 0.f, s4 = 0.f;
    for (int idx = t; idx < nblk; idx += NTHR) {
        s0 += partials[0 * nblk + idx];
        s1 += partials[1 * nblk + idx];
        s2 += partials[2 * nblk + idx];
        s3 += partials[3 * nblk + idx];
        s4 += partials[4 * nblk + idx];
    }
    #pragma unroll
    for (int off = 32; off; off >>= 1) {
        s0 += __shfl_xor(s0, off); s1 += __shfl_xor(s1, off);
        s2 += __shfl_xor(s2, off); s3 += __shfl_xor(s3, off);
        s4 += __shfl_xor(s4, off);
    }
    if ((t & 63) == 0) {
        wred[wv][0] = s0; wred[wv][1] = s1; wred[wv][2] = s2;
        wred[wv][3] = s3; wred[wv][4] = s4;
    }
    __syncthreads();
    if (t == 0) {
        float ce_sum = wred[0][0] + wred[1][0] + wred[2][0] + wred[3][0];
        float vcnt   = wred[0][1] + wred[1][1] + wred[2][1] + wred[3][1];
        float r2_sum = wred[0][2] + wred[1][2] + wred[2][2] + wred[3][2];
        float tvs    = wred[0][3] + wred[1][3] + wred[2][3] + wred[3][3];
        float evo_s  = wred[0][4] + wred[1][4] + wred[2][4] + wred[3][4];
        float ce_loss = (vcnt > 0.f) ? (ce_sum / fmaxf(vcnt, 1.f)) : ce_sum;
        float r2_loss = 0.1f * ((tvs > 0.f) ? (r2_sum / fmaxf(tvs, 1.f)) : r2_sum);
        float evo = 10.f * (evo_s / 32.f);
        if (!isfinite(evo)) evo = 0.f;
        out[0] = 1000.f * (ce_loss + r2_loss + evo);
    }
}

extern "C" void kernel_launch(void* const* d_in, const int* in_sizes, int n_in,
                              void* d_out, int out_size, void* d_ws, size_t ws_size,
                              hipStream_t stream) {
    const float* logits = (const float*)d_in[0];
    const float* prob   = (const float*)d_in[1];
    const float* y_true = (const float*)d_in[2];
    const float* yevo   = (const float*)d_in[3];
    float* out = (float*)d_out;

    const int L = in_sizes[0] / (B * C);   // 4096
    const int nblk = L / TL;               // 512

    float* partials   = (float*)d_ws;                  // 5*nblk floats
    unsigned* counter = (unsigned*)((float*)d_ws + 5 * nblk);

    hipMemsetAsync(counter, 0, sizeof(unsigned), stream);
    k_all<<<nblk, NTHR, 0, stream>>>(logits, prob, y_true, yevo,
                                     partials, counter, out, L, nblk);
}

// Round 5
// 15.334 us; speedup vs baseline: 3.7306x; 3.7306x over previous
//
#include <hip/hip_runtime.h>
#include <math.h>

#define B 32
#define C 4
#define CF 5
#define WPB 16          // waves per block; each wave handles one l
#define NTHR (WPB * 64)

// Main kernel: per-block w-table (1 elem/thread), per-lane row ownership,
// all-pairs JS via 8 in-register rotation steps (shfl), CE + R2 inline.
__global__ __launch_bounds__(NTHR) void k_main(const float* __restrict__ logits,
                                               const float* __restrict__ prob,
                                               const float* __restrict__ y_true,
                                               const float* __restrict__ yevo,
                                               float* __restrict__ partials,
                                               int L) {
    const int t = threadIdx.x;
    const int lane = t & 63;
    const int g = lane >> 5;            // 0: d=1..8, 1: d=9..16
    const int b = lane & 31;            // owned batch row
    const int wv = t >> 6;              // wave id in block
    const int l = (blockIdx.x << 4) | wv;

    __shared__ float w[1024];
    __shared__ float wred[WPB][5];

    // ---- phase 0: w[i][j] = exp(-2y)/(rowsum+eps); one element per thread --
    {
        float e = __expf(-2.0f * yevo[t]);
        float s = e;
        s += __shfl_xor(s, 1);
        s += __shfl_xor(s, 2);
        s += __shfl_xor(s, 4);
        s += __shfl_xor(s, 8);
        s += __shfl_xor(s, 16);         // rowsum over 32 lanes (i = t>>5)
        w[t] = e / (s + 1e-8f);
    }

    // ---- phase 1: per-lane row load (registers), CE + R2 ----
    float ce = 0.f, valid = 0.f, r2s = 0.f, tv = 0.f;

    const float* yt = y_true + ((size_t)b * L + l) * CF;
    float y0 = yt[0], y1 = yt[1], y2 = yt[2], y3 = yt[3], y4 = yt[4];
    int lbl = 0; float best = y0;
    if (y1 > best) { best = y1; lbl = 1; }
    if (y2 > best) { best = y2; lbl = 2; }
    if (y3 > best) { best = y3; lbl = 3; }
    if (y4 > best) { best = y4; lbl = 4; }
    float salt = y1 + y2 + y3;

    float4 pv = *(const float4*)(prob + ((size_t)b * L + l) * C);
    float spalt = pv.y + pv.z + pv.w;           // raw probs per reference
    float q0 = fmaxf(pv.x, 1e-7f), q1 = fmaxf(pv.y, 1e-7f);
    float q2 = fmaxf(pv.z, 1e-7f), q3 = fmaxf(pv.w, 1e-7f);
    float plp = q0 * __logf(q0) + q1 * __logf(q1)
              + q2 * __logf(q2) + q3 * __logf(q3);

    if (g == 0) {
        if (lbl != 4) {
            float4 av = *(const float4*)(logits + ((size_t)b * L + l) * C);
            float mx = fmaxf(fmaxf(av.x, av.y), fmaxf(av.z, av.w));
            float se = __expf(av.x - mx) + __expf(av.y - mx)
                     + __expf(av.z - mx) + __expf(av.w - mx);
            float lse = mx + __logf(se);
            float al = (lbl == 0) ? av.x : (lbl == 1) ? av.y
                     : (lbl == 2) ? av.z : av.w;
            ce = lse - al;
            valid = 1.f;
        }
        // R2: groups of 4 = b bits 0,1 (= lane bits 0,1; partners stay in g0)
        float nmc = (lbl != 4) ? 1.f : 0.f, altc = salt, ps = spalt;
        nmc  += __shfl_xor(nmc, 1);   nmc  += __shfl_xor(nmc, 2);
        altc += __shfl_xor(altc, 1);  altc += __shfl_xor(altc, 2);
        ps   += __shfl_xor(ps, 1);    ps   += __shfl_xor(ps, 2);
        float af = altc / fmaxf(nmc, 1.f);
        float pred = 0.25f * ps;
        bool miss = (lbl == 4);
        float taf = miss ? 0.5f : af;
        bool edge = (taf == 0.f) || (taf == 1.f);
        float denom = fmaxf(taf * (1.f - taf), 0.01f);
        float d = pred - taf;
        float r2 = d * d / denom;
        if (edge || miss) r2 = 0.f;
        r2s -= r2;
        if (nmc > 0.f && r2 != 0.f) tv += 1.f;
    }

    __syncthreads();                    // w table ready

    // ---- phase 2: 8 rotation steps; this half-wave covers d = 1+8g .. 8+8g --
    float evo = 0.f;
    #pragma unroll
    for (int it = 0; it < 8; ++it) {
        int d = 1 + it + (g << 3);
        int jj = (b + d) & 31;
        int src = (lane & 32) | jj;
        float qj0 = __shfl(q0, src), qj1 = __shfl(q1, src);
        float qj2 = __shfl(q2, src), qj3 = __shfl(q3, src);
        float pj  = __shfl(plp, src);
        int   lj  = __shfl(lbl, src);
        float m0 = 0.5f * (q0 + qj0), m1 = 0.5f * (q1 + qj1);
        float m2 = 0.5f * (q2 + qj2), m3 = 0.5f * (q3 + qj3);
        float mlogm = m0 * __logf(m0) + m1 * __logf(m1)
                    + m2 * __logf(m2) + m3 * __logf(m3);
        float js = 0.5f * (plp + pj) - mlogm;
        bool act = (lbl == lj) && (lbl != 4) && !((d == 16) & (b >= 16));
        float wf = act ? (w[(b << 5) + jj] + w[(jj << 5) + b]) : 0.f;
        evo = fmaf(wf, js, evo);
    }

    // ---- wave reduction of 5 accumulators ----
    #pragma unroll
    for (int off = 32; off; off >>= 1) {
        ce += __shfl_xor(ce, off);   valid += __shfl_xor(valid, off);
        r2s += __shfl_xor(r2s, off); tv += __shfl_xor(tv, off);
        evo += __shfl_xor(evo, off);
    }
    if (lane == 0) {
        wred[wv][0] = ce; wred[wv][1] = valid; wred[wv][2] = r2s;
        wred[wv][3] = tv; wred[wv][4] = evo;
    }
    __syncthreads();

    // ---- cross-wave reduction (16 waves) by wave 0, lanes 0..15 ----
    if (t < 16) {
        float a0 = wred[t][0], a1 = wred[t][1], a2 = wred[t][2],
              a3 = wred[t][3], a4 = wred[t][4];
        a0 += __shfl_xor(a0, 1); a1 += __shfl_xor(a1, 1);
        a2 += __shfl_xor(a2, 1); a3 += __shfl_xor(a3, 1);
        a4 += __shfl_xor(a4, 1);
        a0 += __shfl_xor(a0, 2); a1 += __shfl_xor(a1, 2);
        a2 += __shfl_xor(a2, 2); a3 += __shfl_xor(a3, 2);
        a4 += __shfl_xor(a4, 2);
        a0 += __shfl_xor(a0, 4); a1 += __shfl_xor(a1, 4);
        a2 += __shfl_xor(a2, 4); a3 += __shfl_xor(a3, 4);
        a4 += __shfl_xor(a4, 4);
        a0 += __shfl_xor(a0, 8); a1 += __shfl_xor(a1, 8);
        a2 += __shfl_xor(a2, 8); a3 += __shfl_xor(a3, 8);
        a4 += __shfl_xor(a4, 8);
        if (t == 0) {
            float* p = partials + (size_t)blockIdx.x * 8;
            p[0] = a0; p[1] = a1; p[2] = a2; p[3] = a3; p[4] = a4;
        }
    }
}

// Epilogue kernel: 256 block-partials -> scalar loss.
__global__ __launch_bounds__(256) void k_final(const float* __restrict__ partials,
                                               float* __restrict__ out, int nblk) {
    __shared__ float wred[4][5];
    const int t = threadIdx.x;
    float s0 = 0.f, s1 = 0.f, s2 = 0.f, s3 = 0.f, s4 = 0.f;
    if (t < nblk) {
        const float* p = partials + (size_t)t * 8;
        s0 = p[0]; s1 = p[1]; s2 = p[2]; s3 = p[3]; s4 = p[4];
    }
    #pragma unroll
    for (int off = 32; off; off >>= 1) {
        s0 += __shfl_xor(s0, off); s1 += __shfl_xor(s1, off);
        s2 += __shfl_xor(s2, off); s3 += __shfl_xor(s3, off);
        s4 += __shfl_xor(s4, off);
    }
    const int wv = t >> 6;
    if ((t & 63) == 0) {
        wred[wv][0] = s0; wred[wv][1] = s1; wred[wv][2] = s2;
        wred[wv][3] = s3; wred[wv][4] = s4;
    }
    __syncthreads();
    if (t == 0) {
        float ce_sum = wred[0][0] + wred[1][0] + wred[2][0] + wred[3][0];
        float vcnt   = wred[0][1] + wred[1][1] + wred[2][1] + wred[3][1];
        float r2_sum = wred[0][2] + wred[1][2] + wred[2][2] + wred[3][2];
        float tvs    = wred[0][3] + wred[1][3] + wred[2][3] + wred[3][3];
        float evo_s  = wred[0][4] + wred[1][4] + wred[2][4] + wred[3][4];
        float ce_loss = (vcnt > 0.f) ? (ce_sum / fmaxf(vcnt, 1.f)) : ce_sum;
        float r2_loss = 0.1f * ((tvs > 0.f) ? (r2_sum / fmaxf(tvs, 1.f)) : r2_sum);
        float evo = 10.f * (evo_s / 32.f);
        if (!isfinite(evo)) evo = 0.f;
        out[0] = 1000.f * (ce_loss + r2_loss + evo);
    }
}

extern "C" void kernel_launch(void* const* d_in, const int* in_sizes, int n_in,
                              void* d_out, int out_size, void* d_ws, size_t ws_size,
                              hipStream_t stream) {
    const float* logits = (const float*)d_in[0];
    const float* prob   = (const float*)d_in[1];
    const float* y_true = (const float*)d_in[2];
    const float* yevo   = (const float*)d_in[3];
    float* out = (float*)d_out;

    const int L = in_sizes[0] / (B * C);   // 4096
    const int nblk = L / WPB;              // 256

    float* partials = (float*)d_ws;        // nblk * 8 floats

    k_main<<<nblk, NTHR, 0, stream>>>(logits, prob, y_true, yevo, partials, L);
    k_final<<<1, 256, 0, stream>>>(partials, out, nblk);
}